// Round 1
// baseline (1293.098 us; speedup 1.0000x reference)
//
#include <hip/hip_runtime.h>
#include <hip/hip_bf16.h>
#include <math.h>

#define T_AUDIO 441000
#define NFFT 4096
#define NH   2048
#define HOP  1024
#define NBINS 2049
#define NFRAMES 431
#define FP   2080      // padded f stride (mult of 32)
#define TP   448       // padded frame count for X (mult of 64)
#define OUTLEN 444416  // 4096 + 1024*430
#define PAD  2048

#define TWO_PI 6.2831853071795864769f

__device__ __forceinline__ float hann_w(int m) {
    return 0.5f - 0.5f * cosf((float)m * (TWO_PI / 4096.0f));
}

// Stockham radix-2 FFT, length 2048, 256 threads, ping-pong LDS buffers.
// sign = -1 forward, +1 inverse (unnormalized). Returns pointer holding result.
__device__ float2* fft2048(float2* x, float2* y, int tid, float sign) {
    int n = 2048;
    int ls = 0; // log2(s)
    while (n > 1) {
        int m = n >> 1;
        int s = 1 << ls;
        for (int idx = tid; idx < 1024; idx += 256) {
            int q = idx & (s - 1);
            int p = idx >> ls;
            float2 a = x[q + s * p];
            float2 b = x[q + s * (p + m)];
            float ang = sign * (TWO_PI * (float)p / (float)n);
            float sw, cw;
            sincosf(ang, &sw, &cw);
            float2 dif = make_float2(a.x - b.x, a.y - b.y);
            y[q + s * 2 * p]       = make_float2(a.x + b.x, a.y + b.y);
            y[q + s * (2 * p + 1)] = make_float2(cw * dif.x - sw * dif.y,
                                                 cw * dif.y + sw * dif.x);
        }
        __syncthreads();
        float2* t = x; x = y; y = t;
        n = m; ls++;
    }
    return x;
}

// One block per (nc, frame): windowed 4096-pt rfft via packed 2048 complex FFT.
// Writes X=|mix| (padded [4][TP][FP]) and phase re/im ([4][431][FP]).
__global__ __launch_bounds__(256) void k_stft(const float* __restrict__ audio,
        float* __restrict__ X, float* __restrict__ phr, float* __restrict__ phi) {
    __shared__ float2 bufA[2048];
    __shared__ float2 bufB[2048];
    int blk = blockIdx.x;
    int nc = blk / NFRAMES;
    int fr = blk - nc * NFRAMES;
    const float* a = audio + (size_t)nc * T_AUDIO;
    int tid = threadIdx.x;
    int base = fr * HOP - PAD;  // start index in (unpadded) signal coords
    for (int m = tid; m < NH; m += 256) {
        int r0 = base + 2 * m;
        int r1 = r0 + 1;
        r0 = r0 < 0 ? -r0 : (r0 >= T_AUDIO ? 2 * T_AUDIO - 2 - r0 : r0);
        r1 = r1 < 0 ? -r1 : (r1 >= T_AUDIO ? 2 * T_AUDIO - 2 - r1 : r1);
        float x0 = a[r0] * hann_w(2 * m);
        float x1 = a[r1] * hann_w(2 * m + 1);
        bufA[m] = make_float2(x0, x1);
    }
    __syncthreads();
    float2* res = fft2048(bufA, bufB, tid, -1.0f);
    size_t orow = ((size_t)nc * NFRAMES + fr) * FP;
    float* Xrow = X + ((size_t)nc * TP + fr) * FP;
    for (int k = tid; k < NBINS; k += 256) {
        float2 Zk = res[k & 2047];
        float2 Zm = res[(2048 - k) & 2047];
        float ex = 0.5f * (Zk.x + Zm.x), ey = 0.5f * (Zk.y - Zm.y);
        float ox = 0.5f * (Zk.y + Zm.y), oy = -0.5f * (Zk.x - Zm.x);
        float sw, cw;
        sincosf((float)k * (TWO_PI / 4096.0f), &sw, &cw);
        // W = cw - i*sw ; bin = E + W*O
        float re = ex + cw * ox + sw * oy;
        float im = ey + cw * oy - sw * ox;
        float mag = sqrtf(re * re + im * im);
        float inv = 1.0f / (mag + 1e-10f);
        Xrow[k] = mag;
        phr[orow + k] = re * inv;
        phi[orow + k] = im * inv;
    }
}

// V[j,nc,t,g] = relu(sum_f W[j,g,f] * X[nc,t,f] + b[j,g])
// Simple fp32 tiled GEMM: 64(g) x 64(t) tile, BK=32, 256 threads, 4x4 microtile.
__global__ __launch_bounds__(256) void k_gemm(const float* __restrict__ Wm,
        const float* __restrict__ bias, const float* __restrict__ X,
        float* __restrict__ V) {
    int j  = blockIdx.z >> 2;
    int nc = blockIdx.z & 3;
    int g0 = blockIdx.x * 64;
    int t0 = blockIdx.y * 64;
    const float* A = Wm + (size_t)j * 2049 * 2049;
    const float* B = X + (size_t)nc * TP * FP;
    __shared__ float As[32][68];
    __shared__ float Bs[32][68];
    int tid = threadIdx.x;
    int tx = tid & 15, ty = tid >> 4;
    float acc[4][4] = {};
    for (int k0 = 0; k0 < FP; k0 += 32) {
        // A: 64 rows x 32 cols, scalar loads (rows of W are odd-length -> no 16B align)
        {
            int row8 = tid >> 5;        // 0..7
            int col = tid & 31;         // 0..31
            int f = k0 + col;
            bool fv = (f < 2049);
            #pragma unroll
            for (int e = 0; e < 8; e++) {
                int row = row8 + e * 8;
                int g = g0 + row;
                float v = (fv && g < 2049) ? A[(size_t)g * 2049 + f] : 0.0f;
                As[col][row] = v;
            }
        }
        // B: 64 rows x 32 cols, float4 (X is padded+aligned, pad area zeroed)
        #pragma unroll
        for (int e = 0; e < 2; e++) {
            int L = e * 256 + tid;
            int row = L >> 3, c4 = L & 7;
            int f = k0 + c4 * 4;
            float4 u = *reinterpret_cast<const float4*>(&B[(size_t)(t0 + row) * FP + f]);
            Bs[c4 * 4 + 0][row] = u.x; Bs[c4 * 4 + 1][row] = u.y;
            Bs[c4 * 4 + 2][row] = u.z; Bs[c4 * 4 + 3][row] = u.w;
        }
        __syncthreads();
        #pragma unroll
        for (int k = 0; k < 32; k++) {
            float4 av = *reinterpret_cast<const float4*>(&As[k][tx * 4]);
            float4 bv = *reinterpret_cast<const float4*>(&Bs[k][ty * 4]);
            float aa[4] = {av.x, av.y, av.z, av.w};
            float bb[4] = {bv.x, bv.y, bv.z, bv.w};
            #pragma unroll
            for (int i = 0; i < 4; i++)
                #pragma unroll
                for (int jj = 0; jj < 4; jj++)
                    acc[i][jj] += aa[i] * bb[jj];
        }
        __syncthreads();
    }
    int jnc = blockIdx.z;  // j*4+nc
    #pragma unroll
    for (int jj = 0; jj < 4; jj++) {
        int t = t0 + ty * 4 + jj;
        if (t >= NFRAMES) continue;
        size_t vrow = ((size_t)jnc * NFRAMES + t) * FP;
        #pragma unroll
        for (int i = 0; i < 4; i++) {
            int g = g0 + tx * 4 + i;
            if (g < 2049) {
                float val = acc[i][jj] + bias[j * 2049 + g];
                V[vrow + g] = fmaxf(val, 0.0f);
            }
        }
    }
}

// One block per (njc, frame): Y = V*phase, 4096-pt irfft, window, += into acc.
// Frames within one pass are 4 apart -> disjoint output ranges -> no atomics.
__global__ __launch_bounds__(256) void k_istft(const float* __restrict__ V,
        const float* __restrict__ phr, const float* __restrict__ phi,
        float* __restrict__ acc, int pass) {
    int fr = pass + 4 * blockIdx.x;
    if (fr >= NFRAMES) return;
    int njc = blockIdx.y;
    int n = njc >> 3, j = (njc >> 1) & 3, c = njc & 1;
    int nc = n * 2 + c;
    __shared__ float2 yb[2049];
    __shared__ float2 zb[2048];
    int tid = threadIdx.x;
    size_t vrow = (((size_t)(j * 4 + nc)) * NFRAMES + fr) * FP;
    size_t prow = ((size_t)nc * NFRAMES + fr) * FP;
    for (int k = tid; k < NBINS; k += 256) {
        float v = V[vrow + k];
        yb[k] = make_float2(v * phr[prow + k], v * phi[prow + k]);
    }
    __syncthreads();
    for (int k = tid; k < NH; k += 256) {
        float2 Yk = yb[k];
        float2 Ym = yb[2048 - k];
        float ex = 0.5f * (Yk.x + Ym.x), ey = 0.5f * (Yk.y - Ym.y);
        float wx = 0.5f * (Yk.x - Ym.x), wy = 0.5f * (Yk.y + Ym.y);
        float sw, cw;
        sincosf((float)k * (TWO_PI / 4096.0f), &sw, &cw);
        float ox_ = cw * wx - sw * wy;   // O = e^{+i a} * Wo
        float oy_ = cw * wy + sw * wx;
        zb[k] = make_float2(ex - oy_, ey + ox_);
    }
    __syncthreads();
    float2* res = fft2048(zb, yb, tid, +1.0f);
    float* dst = acc + (size_t)njc * OUTLEN + (size_t)fr * HOP;
    const float scale = 1.0f / 2048.0f;
    for (int m = tid; m < NH; m += 256) {
        float2 z = res[m];
        int m2 = 2 * m;
        dst[m2]     += z.x * scale * hann_w(m2);
        dst[m2 + 1] += z.y * scale * hann_w(m2 + 1);
    }
}

// out = acc[q] / wsq(q), q = t + 2048
__global__ __launch_bounds__(256) void k_final(const float* __restrict__ acc,
        float* __restrict__ out) {
    int t = blockIdx.x * 256 + threadIdx.x;
    int njc = blockIdx.y;
    if (t >= T_AUDIO) return;
    int q = t + PAD;
    int ib = q >> 10;
    float wsq = 0.0f;
    #pragma unroll
    for (int d = 0; d < 4; d++) {
        int i = ib - d;
        if (i >= 0 && i <= NFRAMES - 1) {
            int m = q - (i << 10);
            float w = hann_w(m);
            wsq += w * w;
        }
    }
    if (!(wsq > 1e-11f)) wsq = 1.0f;
    out[(size_t)njc * T_AUDIO + t] = acc[(size_t)njc * OUTLEN + q] / wsq;
}

extern "C" void kernel_launch(void* const* d_in, const int* in_sizes, int n_in,
                              void* d_out, int out_size, void* d_ws, size_t ws_size,
                              hipStream_t stream) {
    const float* audio = (const float*)d_in[0];
    const float* Wm    = (const float*)d_in[1];
    const float* bias  = (const float*)d_in[2];
    float* out = (float*)d_out;
    float* ws  = (float*)d_ws;

    size_t oX   = 0;
    size_t oPhr = oX   + (size_t)4 * TP * FP;        // X:   [4][448][2080]
    size_t oPhi = oPhr + (size_t)4 * NFRAMES * FP;   // phr: [4][431][2080]
    size_t oV   = oPhi + (size_t)4 * NFRAMES * FP;   // phi: [4][431][2080]
    size_t oAcc = oV   + (size_t)16 * NFRAMES * FP;  // V:   [16][431][2080]
    size_t need = (oAcc + (size_t)16 * OUTLEN) * sizeof(float);
    if (ws_size < need) return;  // insufficient workspace; bail (will fail validation)

    float* X    = ws + oX;
    float* phr  = ws + oPhr;
    float* phi  = ws + oPhi;
    float* V    = ws + oV;
    float* accb = ws + oAcc;

    hipMemsetAsync(X, 0, (size_t)4 * TP * FP * sizeof(float), stream);
    hipMemsetAsync(accb, 0, (size_t)16 * OUTLEN * sizeof(float), stream);

    k_stft<<<dim3(4 * NFRAMES), 256, 0, stream>>>(audio, X, phr, phi);
    k_gemm<<<dim3(33, 7, 16), 256, 0, stream>>>(Wm, bias, X, V);
    for (int pass = 0; pass < 4; pass++)
        k_istft<<<dim3(108, 16), 256, 0, stream>>>(V, phr, phi, accb, pass);
    k_final<<<dim3((T_AUDIO + 255) / 256, 16), 256, 0, stream>>>(accb, out);
}

// Round 2
// 410.023 us; speedup vs baseline: 3.1537x; 3.1537x over previous
//
#include <hip/hip_runtime.h>
#include <hip/hip_bf16.h>
#include <math.h>

#define T_AUDIO 441000
#define NFFT 4096
#define NH   2048
#define HOP  1024
#define NBINS 2049
#define NFRAMES 431
#define OUTLEN 444416  // 4096 + 1024*430
#define PAD  2048

// GEMM padded dims (bf16 buffers, zero-filled padding -> no guards in GEMM)
#define GP  2176   // padded g (M) = 17*128
#define KP  2080   // padded f (K), mult of 32
#define TPN 512    // padded frames (N) = 4*128

#define TWO_PI 6.2831853071795864769f

typedef __bf16 bf16_t;
typedef bf16_t bf16x8 __attribute__((ext_vector_type(8)));
typedef bf16_t bf16x4 __attribute__((ext_vector_type(4)));
typedef float f32x4 __attribute__((ext_vector_type(4)));

__device__ __forceinline__ float hann_w(int m) {
    return 0.5f - 0.5f * __cosf((float)m * (TWO_PI / 4096.0f));
}

__device__ __forceinline__ unsigned pack_bf2(float a, float b) {
    union { bf16_t h; unsigned short u; } ca, cb;
    ca.h = (bf16_t)a; cb.h = (bf16_t)b;
    return (unsigned)ca.u | ((unsigned)cb.u << 16);
}
__device__ __forceinline__ float2 unpack_bf2(unsigned v) {
    union { unsigned u; float f; } a, b;
    a.u = v << 16;
    b.u = v & 0xffff0000u;
    return make_float2(a.f, b.f);
}

// Stockham radix-2 FFT, length 2048, 256 threads, ping-pong LDS buffers.
__device__ float2* fft2048(float2* x, float2* y, int tid, float sign) {
    int n = 2048;
    int ls = 0;
    while (n > 1) {
        int m = n >> 1;
        int s = 1 << ls;
        for (int idx = tid; idx < 1024; idx += 256) {
            int q = idx & (s - 1);
            int p = idx >> ls;
            float2 a = x[q + s * p];
            float2 b = x[q + s * (p + m)];
            float ang = sign * (TWO_PI * (float)p / (float)n);
            float sw, cw;
            __sincosf(ang, &sw, &cw);
            float2 dif = make_float2(a.x - b.x, a.y - b.y);
            y[q + s * 2 * p]       = make_float2(a.x + b.x, a.y + b.y);
            y[q + s * (2 * p + 1)] = make_float2(cw * dif.x - sw * dif.y,
                                                 cw * dif.y + sw * dif.x);
        }
        __syncthreads();
        float2* t = x; x = y; y = t;
        n = m; ls++;
    }
    return x;
}

// One block per (nc, frame): windowed 4096-pt rfft via packed 2048 complex FFT.
// Writes Xb=|mix| (bf16, padded [4][TPN][KP]) and packed bf16 phase ([4][431][KP]).
__global__ __launch_bounds__(256) void k_stft(const float* __restrict__ audio,
        bf16_t* __restrict__ Xb, unsigned* __restrict__ ph) {
    __shared__ float2 bufA[2048];
    __shared__ float2 bufB[2048];
    int blk = blockIdx.x;
    int nc = blk / NFRAMES;
    int fr = blk - nc * NFRAMES;
    const float* a = audio + (size_t)nc * T_AUDIO;
    int tid = threadIdx.x;
    int base = fr * HOP - PAD;
    for (int m = tid; m < NH; m += 256) {
        int r0 = base + 2 * m;
        int r1 = r0 + 1;
        r0 = r0 < 0 ? -r0 : (r0 >= T_AUDIO ? 2 * T_AUDIO - 2 - r0 : r0);
        r1 = r1 < 0 ? -r1 : (r1 >= T_AUDIO ? 2 * T_AUDIO - 2 - r1 : r1);
        float x0 = a[r0] * hann_w(2 * m);
        float x1 = a[r1] * hann_w(2 * m + 1);
        bufA[m] = make_float2(x0, x1);
    }
    __syncthreads();
    float2* res = fft2048(bufA, bufB, tid, -1.0f);
    size_t orow = ((size_t)nc * NFRAMES + fr) * KP;
    bf16_t* Xrow = Xb + ((size_t)nc * TPN + fr) * KP;
    for (int k = tid; k < NBINS; k += 256) {
        float2 Zk = res[k & 2047];
        float2 Zm = res[(2048 - k) & 2047];
        float ex = 0.5f * (Zk.x + Zm.x), ey = 0.5f * (Zk.y - Zm.y);
        float ox = 0.5f * (Zk.y + Zm.y), oy = -0.5f * (Zk.x - Zm.x);
        float sw, cw;
        __sincosf((float)k * (TWO_PI / 4096.0f), &sw, &cw);
        float re = ex + cw * ox + sw * oy;
        float im = ey + cw * oy - sw * ox;
        float mag = sqrtf(re * re + im * im);
        float inv = 1.0f / (mag + 1e-10f);
        Xrow[k] = (bf16_t)mag;
        ph[orow + k] = pack_bf2(re * inv, im * inv);
    }
}

// W [4][2049][2049] fp32 -> Wb [4][GP][KP] bf16, zero-pad.
__global__ __launch_bounds__(256) void k_convW(const float* __restrict__ W,
        bf16_t* __restrict__ Wb) {
    size_t idx = (size_t)blockIdx.x * 256 + threadIdx.x;
    size_t total = (size_t)4 * GP * KP / 8;
    if (idx >= total) return;
    size_t e = idx * 8;
    int f0 = (int)(e % KP);
    size_t rem = e / KP;
    int g = (int)(rem % GP);
    int j = (int)(rem / GP);
    bf16x8 v = {};
    if (g < NBINS) {
        const float* src = W + ((size_t)j * NBINS + g) * NBINS;
        #pragma unroll
        for (int r = 0; r < 8; r++) {
            int f = f0 + r;
            v[r] = (bf16_t)(f < NBINS ? src[f] : 0.0f);
        }
    }
    *(bf16x8*)(Wb + e) = v;
}

// V[jnc][t][g] = relu(sum_f W[j][g][f]*X[nc][t][f] + b[j][g]), bf16 out.
// m97-style: 128x128 tile, BK=32, 4 waves (2x2), mfma 16x16x32 bf16, 4x4 frags.
__global__ __launch_bounds__(256) void k_gemm_mfma(const bf16_t* __restrict__ Wb,
        const float* __restrict__ bias, const bf16_t* __restrict__ Xb,
        bf16_t* __restrict__ V) {
    __shared__ bf16_t As[128 * 32];
    __shared__ bf16_t Bs[128 * 32];
    int j  = blockIdx.z >> 2;
    int jnc = blockIdx.z;
    int g0 = blockIdx.x * 128;
    int t0 = blockIdx.y * 128;
    const bf16_t* A = Wb + (size_t)j * GP * KP;
    const bf16_t* B = Xb + (size_t)(blockIdx.z & 3) * TPN * KP;
    int tid = threadIdx.x;
    int lane = tid & 63, wid = tid >> 6;
    int wm = wid >> 1, wn = wid & 1;   // 2x2 waves, each 64x64

    // staging addresses: thread tid copies 16B; tile is 128 rows x 32 cols bf16
    int rowS = tid >> 2;               // 0..63 (32 elems/row, 4 threads/row)
    int colS = (tid & 3) * 8;
    const bf16_t* gA0 = A + (size_t)(g0 + rowS) * KP + colS;
    const bf16_t* gA1 = A + (size_t)(g0 + rowS + 64) * KP + colS;
    const bf16_t* gB0 = B + (size_t)(t0 + rowS) * KP + colS;
    const bf16_t* gB1 = B + (size_t)(t0 + rowS + 64) * KP + colS;
    bf16_t* lA0 = As + tid * 8;
    bf16_t* lA1 = As + 2048 + tid * 8;
    bf16_t* lB0 = Bs + tid * 8;
    bf16_t* lB1 = Bs + 2048 + tid * 8;

    int rA = lane & 15;
    int kc = (lane >> 4) * 8;
    const bf16_t* aBase = As + (wm * 64 + rA) * 32 + kc;
    const bf16_t* bBase = Bs + (wn * 64 + rA) * 32 + kc;

    f32x4 acc[4][4];
    #pragma unroll
    for (int m = 0; m < 4; m++)
        #pragma unroll
        for (int n = 0; n < 4; n++)
            acc[m][n] = (f32x4){0.f, 0.f, 0.f, 0.f};

    for (int k0 = 0; k0 < KP; k0 += 32) {
        __builtin_amdgcn_global_load_lds(
            (const __attribute__((address_space(1))) void*)(gA0 + k0),
            (__attribute__((address_space(3))) void*)lA0, 16, 0, 0);
        __builtin_amdgcn_global_load_lds(
            (const __attribute__((address_space(1))) void*)(gA1 + k0),
            (__attribute__((address_space(3))) void*)lA1, 16, 0, 0);
        __builtin_amdgcn_global_load_lds(
            (const __attribute__((address_space(1))) void*)(gB0 + k0),
            (__attribute__((address_space(3))) void*)lB0, 16, 0, 0);
        __builtin_amdgcn_global_load_lds(
            (const __attribute__((address_space(1))) void*)(gB1 + k0),
            (__attribute__((address_space(3))) void*)lB1, 16, 0, 0);
        __syncthreads();

        bf16x8 af[4], bfr[4];
        #pragma unroll
        for (int m = 0; m < 4; m++)
            af[m] = *(const bf16x8*)(aBase + m * 512);
        #pragma unroll
        for (int n = 0; n < 4; n++)
            bfr[n] = *(const bf16x8*)(bBase + n * 512);
        #pragma unroll
        for (int m = 0; m < 4; m++)
            #pragma unroll
            for (int n = 0; n < 4; n++)
                acc[m][n] = __builtin_amdgcn_mfma_f32_16x16x32_bf16(
                    af[m], bfr[n], acc[m][n], 0, 0, 0);
        __syncthreads();
    }

    // epilogue: C row = g (M), col = t (N); col=lane&15, row=(lane>>4)*4+reg
    int colT = lane & 15;
    int rowB = (lane >> 4) * 4;
    #pragma unroll
    for (int n = 0; n < 4; n++) {
        int t = t0 + wn * 64 + n * 16 + colT;
        if (t >= NFRAMES) continue;
        size_t vrow = ((size_t)jnc * NFRAMES + t) * KP;
        #pragma unroll
        for (int m = 0; m < 4; m++) {
            int g = g0 + wm * 64 + m * 16 + rowB;
            if (g + 3 < NBINS) {
                bf16x4 o;
                #pragma unroll
                for (int r = 0; r < 4; r++)
                    o[r] = (bf16_t)fmaxf(acc[m][n][r] + bias[j * NBINS + g + r], 0.0f);
                *(bf16x4*)(V + vrow + g) = o;
            } else {
                #pragma unroll
                for (int r = 0; r < 4; r++) {
                    int gg = g + r;
                    if (gg < NBINS)
                        V[vrow + gg] = (bf16_t)fmaxf(acc[m][n][r] + bias[j * NBINS + gg], 0.0f);
                }
            }
        }
    }
}

// One block per (njc, frame): Y = V*phase, 4096-pt irfft, window, += into acc.
__global__ __launch_bounds__(256) void k_istft(const bf16_t* __restrict__ V,
        const unsigned* __restrict__ ph, float* __restrict__ acc, int pass) {
    int fr = pass + 4 * blockIdx.x;
    if (fr >= NFRAMES) return;
    int njc = blockIdx.y;
    int n = njc >> 3, j = (njc >> 1) & 3, c = njc & 1;
    int nc = n * 2 + c;
    __shared__ float2 yb[2049];
    __shared__ float2 zb[2048];
    int tid = threadIdx.x;
    size_t vrow = (((size_t)(j * 4 + nc)) * NFRAMES + fr) * KP;
    size_t prow = ((size_t)nc * NFRAMES + fr) * KP;
    for (int k = tid; k < NBINS; k += 256) {
        float v = (float)V[vrow + k];
        float2 p = unpack_bf2(ph[prow + k]);
        yb[k] = make_float2(v * p.x, v * p.y);
    }
    __syncthreads();
    for (int k = tid; k < NH; k += 256) {
        float2 Yk = yb[k];
        float2 Ym = yb[2048 - k];
        float ex = 0.5f * (Yk.x + Ym.x), ey = 0.5f * (Yk.y - Ym.y);
        float wx = 0.5f * (Yk.x - Ym.x), wy = 0.5f * (Yk.y + Ym.y);
        float sw, cw;
        __sincosf((float)k * (TWO_PI / 4096.0f), &sw, &cw);
        float ox_ = cw * wx - sw * wy;
        float oy_ = cw * wy + sw * wx;
        zb[k] = make_float2(ex - oy_, ey + ox_);
    }
    __syncthreads();
    float2* res = fft2048(zb, yb, tid, +1.0f);
    float* dst = acc + (size_t)njc * OUTLEN + (size_t)fr * HOP;
    const float scale = 1.0f / 2048.0f;
    for (int m = tid; m < NH; m += 256) {
        float2 z = res[m];
        int m2 = 2 * m;
        dst[m2]     += z.x * scale * hann_w(m2);
        dst[m2 + 1] += z.y * scale * hann_w(m2 + 1);
    }
}

__global__ __launch_bounds__(256) void k_final(const float* __restrict__ acc,
        float* __restrict__ out) {
    int t = blockIdx.x * 256 + threadIdx.x;
    int njc = blockIdx.y;
    if (t >= T_AUDIO) return;
    int q = t + PAD;
    int ib = q >> 10;
    float wsq = 0.0f;
    #pragma unroll
    for (int d = 0; d < 4; d++) {
        int i = ib - d;
        if (i >= 0 && i <= NFRAMES - 1) {
            int m = q - (i << 10);
            float w = hann_w(m);
            wsq += w * w;
        }
    }
    if (!(wsq > 1e-11f)) wsq = 1.0f;
    out[(size_t)njc * T_AUDIO + t] = acc[(size_t)njc * OUTLEN + q] / wsq;
}

extern "C" void kernel_launch(void* const* d_in, const int* in_sizes, int n_in,
                              void* d_out, int out_size, void* d_ws, size_t ws_size,
                              hipStream_t stream) {
    const float* audio = (const float*)d_in[0];
    const float* Wm    = (const float*)d_in[1];
    const float* bias  = (const float*)d_in[2];
    float* out = (float*)d_out;
    char* ws = (char*)d_ws;

    size_t szWb  = (size_t)4 * GP * KP * sizeof(bf16_t);      // 36.2 MB
    size_t szXb  = (size_t)4 * TPN * KP * sizeof(bf16_t);     //  8.5 MB
    size_t szPh  = (size_t)4 * NFRAMES * KP * sizeof(unsigned); // 14.3 MB
    size_t szV   = (size_t)16 * NFRAMES * KP * sizeof(bf16_t);  // 28.7 MB
    size_t szAcc = (size_t)16 * OUTLEN * sizeof(float);         // 28.4 MB

    bf16_t*   Wb   = (bf16_t*)ws;                 ws += szWb;
    bf16_t*   Xb   = (bf16_t*)ws;                 ws += szXb;
    unsigned* ph   = (unsigned*)ws;               ws += szPh;
    bf16_t*   V    = (bf16_t*)ws;                 ws += szV;
    float*    accb = (float*)ws;                  ws += szAcc;
    if ((size_t)(ws - (char*)d_ws) > ws_size) return;

    hipMemsetAsync(Xb, 0, szXb, stream);
    hipMemsetAsync(accb, 0, szAcc, stream);

    k_convW<<<dim3((4 * GP * KP / 8 + 255) / 256), 256, 0, stream>>>(Wm, Wb);
    k_stft<<<dim3(4 * NFRAMES), 256, 0, stream>>>(audio, Xb, ph);
    k_gemm_mfma<<<dim3(GP / 128, TPN / 128, 16), 256, 0, stream>>>(Wb, bias, Xb, V);
    for (int pass = 0; pass < 4; pass++)
        k_istft<<<dim3(108, 16), 256, 0, stream>>>(V, ph, accb, pass);
    k_final<<<dim3((T_AUDIO + 255) / 256, 16), 256, 0, stream>>>(accb, out);
}

// Round 3
// 302.440 us; speedup vs baseline: 4.2756x; 1.3557x over previous
//
#include <hip/hip_runtime.h>
#include <hip/hip_bf16.h>
#include <math.h>

#define T_AUDIO 441000
#define NH   2048
#define HOP  1024
#define NBINS 2049
#define NFRAMES 431
#define OUTLEN 444416  // 4096 + 1024*430
#define PAD  2048

// GEMM padded dims (bf16 buffers, zero-filled padding -> no guards in GEMM)
#define GP  2176   // padded g (M) = 17*128
#define KP  2112   // padded f (K) = 33*64
#define TPN 512    // padded frames per nc (B rows exist up to 512, zeroed)

#define TWO_PI 6.2831853071795864769f

// LDS index padding for FFT buffers: +1 float2 per 16 -> breaks strided conflicts
#define PADI(i) ((i) + ((i) >> 4))

typedef __bf16 bf16_t;
typedef bf16_t bf16x8 __attribute__((ext_vector_type(8)));
typedef bf16_t bf16x4 __attribute__((ext_vector_type(4)));
typedef float f32x4 __attribute__((ext_vector_type(4)));

__device__ __forceinline__ float hann_w(int m) {
    return 0.5f - 0.5f * __cosf((float)m * (TWO_PI / 4096.0f));
}

__device__ __forceinline__ unsigned pack_bf2(float a, float b) {
    union { bf16_t h; unsigned short u; } ca, cb;
    ca.h = (bf16_t)a; cb.h = (bf16_t)b;
    return (unsigned)ca.u | ((unsigned)cb.u << 16);
}
__device__ __forceinline__ float2 unpack_bf2(unsigned v) {
    union { unsigned u; float f; } a, b;
    a.u = v << 16;
    b.u = v & 0xffff0000u;
    return make_float2(a.f, b.f);
}

__device__ __forceinline__ float2 cmul(float2 a, float2 b) {
    return make_float2(a.x * b.x - a.y * b.y, a.x * b.y + a.y * b.x);
}

// Stockham FFT, length 2048: 5 radix-4 stages + 1 radix-2 stage.
// All LDS accesses use PADI. 256 threads. Returns buffer holding result.
__device__ float2* fft2048_r4(float2* x, float2* y, int tid, float sign) {
    int n = 2048;
    int ls = 0;
    #pragma unroll
    for (int st = 0; st < 5; st++) {
        int m = n >> 2;
        int s = 1 << ls;
        #pragma unroll
        for (int it = 0; it < 2; it++) {
            int idx = tid + it * 256;
            int q = idx & (s - 1);
            int p = idx >> ls;
            float2 a = x[PADI(q + s * p)];
            float2 b = x[PADI(q + s * (p + m))];
            float2 c = x[PADI(q + s * (p + 2 * m))];
            float2 d = x[PADI(q + s * (p + 3 * m))];
            float2 t0 = make_float2(a.x + c.x, a.y + c.y);
            float2 t1 = make_float2(a.x - c.x, a.y - c.y);
            float2 t2 = make_float2(b.x + d.x, b.y + d.y);
            float2 t3 = make_float2(b.x - d.x, b.y - d.y);
            float2 it3 = make_float2(-sign * t3.y, sign * t3.x);  // sign*i*t3
            float2 u0 = make_float2(t0.x + t2.x, t0.y + t2.y);
            float2 u2 = make_float2(t0.x - t2.x, t0.y - t2.y);
            float2 u1 = make_float2(t1.x + it3.x, t1.y + it3.y);
            float2 u3 = make_float2(t1.x - it3.x, t1.y - it3.y);
            float ang = sign * (TWO_PI * (float)p / (float)n);
            float sw, cw;
            __sincosf(ang, &sw, &cw);
            float2 w1 = make_float2(cw, sw);
            float2 w2 = cmul(w1, w1);
            float2 w3 = cmul(w2, w1);
            int ob = q + s * 4 * p;
            y[PADI(ob)]         = u0;
            y[PADI(ob + s)]     = cmul(w1, u1);
            y[PADI(ob + 2 * s)] = cmul(w2, u2);
            y[PADI(ob + 3 * s)] = cmul(w3, u3);
        }
        __syncthreads();
        float2* t = x; x = y; y = t;
        n = m; ls += 2;
    }
    // final radix-2 stage: n=2, s=1024, twiddle-free
    #pragma unroll
    for (int it = 0; it < 4; it++) {
        int q = tid + it * 256;
        float2 a = x[PADI(q)], b = x[PADI(q + 1024)];
        y[PADI(q)]        = make_float2(a.x + b.x, a.y + b.y);
        y[PADI(q + 1024)] = make_float2(a.x - b.x, a.y - b.y);
    }
    __syncthreads();
    return y;
}

// One block per (nc, frame): windowed 4096-pt rfft via packed 2048 complex FFT.
__global__ __launch_bounds__(256) void k_stft(const float* __restrict__ audio,
        bf16_t* __restrict__ Xb, unsigned* __restrict__ ph) {
    __shared__ float2 bufA[PADI(2047) + 2];
    __shared__ float2 bufB[PADI(2047) + 2];
    int blk = blockIdx.x;
    int nc = blk / NFRAMES;
    int fr = blk - nc * NFRAMES;
    const float* a = audio + (size_t)nc * T_AUDIO;
    int tid = threadIdx.x;
    int base = fr * HOP - PAD;
    for (int m = tid; m < NH; m += 256) {
        int r0 = base + 2 * m;
        int r1 = r0 + 1;
        r0 = r0 < 0 ? -r0 : (r0 >= T_AUDIO ? 2 * T_AUDIO - 2 - r0 : r0);
        r1 = r1 < 0 ? -r1 : (r1 >= T_AUDIO ? 2 * T_AUDIO - 2 - r1 : r1);
        float x0 = a[r0] * hann_w(2 * m);
        float x1 = a[r1] * hann_w(2 * m + 1);
        bufA[PADI(m)] = make_float2(x0, x1);
    }
    __syncthreads();
    float2* res = fft2048_r4(bufA, bufB, tid, -1.0f);
    size_t orow = ((size_t)nc * NFRAMES + fr) * KP;
    bf16_t* Xrow = Xb + ((size_t)nc * TPN + fr) * KP;
    for (int k = tid; k < NBINS; k += 256) {
        float2 Zk = res[PADI(k & 2047)];
        float2 Zm = res[PADI((2048 - k) & 2047)];
        float ex = 0.5f * (Zk.x + Zm.x), ey = 0.5f * (Zk.y - Zm.y);
        float ox = 0.5f * (Zk.y + Zm.y), oy = -0.5f * (Zk.x - Zm.x);
        float sw, cw;
        __sincosf((float)k * (TWO_PI / 4096.0f), &sw, &cw);
        float re = ex + cw * ox + sw * oy;
        float im = ey + cw * oy - sw * ox;
        float mag = sqrtf(re * re + im * im);
        float inv = 1.0f / (mag + 1e-10f);
        Xrow[k] = (bf16_t)mag;
        ph[orow + k] = pack_bf2(re * inv, im * inv);
    }
}

// W [4][2049][2049] fp32 -> Wb [4][GP][KP] bf16, zero-pad.
__global__ __launch_bounds__(256) void k_convW(const float* __restrict__ W,
        bf16_t* __restrict__ Wb) {
    size_t idx = (size_t)blockIdx.x * 256 + threadIdx.x;
    size_t total = (size_t)4 * GP * KP / 8;
    if (idx >= total) return;
    size_t e = idx * 8;
    int f0 = (int)(e % KP);
    size_t rem = e / KP;
    int g = (int)(rem % GP);
    int j = (int)(rem / GP);
    bf16x8 v = {};
    if (g < NBINS) {
        const float* src = W + ((size_t)j * NBINS + g) * NBINS;
        #pragma unroll
        for (int r = 0; r < 8; r++) {
            int f = f0 + r;
            v[r] = (bf16_t)(f < NBINS ? src[f] : 0.0f);
        }
    }
    *(bf16x8*)(Wb + e) = v;
}

// V[jnc][t][g] = relu(sum_f W[j][g][f]*X[nc][t][f] + b[j][g]), bf16 out.
// BM=128 (g), BN=64 (t), BK=64; 4 waves 2x2 (wave tile 64x32); swizzled LDS
// (chunk c ^= row&7, conflict-free ds_read_b128, staged via pre-swizzled
// global_load_lds source). Grid (28 N-blocks, 17 M, 4 j) = 1904 blocks.
__global__ __launch_bounds__(256) void k_gemm_mfma(const bf16_t* __restrict__ Wb,
        const float* __restrict__ bias, const bf16_t* __restrict__ Xb,
        bf16_t* __restrict__ V) {
    __shared__ bf16_t As[128 * 64];   // 16 KB
    __shared__ bf16_t Bs[64 * 64];    // 8 KB
    int j  = blockIdx.z;
    int bx = blockIdx.x;              // 0..27
    int nc = bx / 7;
    int t0 = (bx - nc * 7) * 64;
    int g0 = blockIdx.y * 128;
    const bf16_t* A = Wb + ((size_t)j * GP + g0) * KP;
    const bf16_t* B = Xb + ((size_t)nc * TPN + t0) * KP;
    int tid = threadIdx.x;
    int lane = tid & 63, wid = tid >> 6;
    int wm = wid >> 1, wn = wid & 1;

    // staging: slot s holds element block (r = s>>3, c = (s&7) ^ (r&7))
    const bf16_t* srcA[4];
    #pragma unroll
    for (int i = 0; i < 4; i++) {
        int s = i * 256 + tid;
        int r = s >> 3, cc = (s & 7) ^ (r & 7);
        srcA[i] = A + (size_t)r * KP + cc * 8;
    }
    const bf16_t* srcB[2];
    #pragma unroll
    for (int i = 0; i < 2; i++) {
        int s = i * 256 + tid;
        int r = s >> 3, cc = (s & 7) ^ (r & 7);
        srcB[i] = B + (size_t)r * KP + cc * 8;
    }

    // fragment read byte-offsets (constant per thread)
    int laneLo = lane & 15, laneHi = lane >> 4;
    int offA[4][2], offB[2][2];
    #pragma unroll
    for (int m = 0; m < 4; m++) {
        int r = wm * 64 + m * 16 + laneLo;
        #pragma unroll
        for (int kk = 0; kk < 2; kk++) {
            int c = kk * 4 + laneHi;
            offA[m][kk] = r * 128 + ((c ^ (r & 7)) << 4);
        }
    }
    #pragma unroll
    for (int n = 0; n < 2; n++) {
        int r = wn * 32 + n * 16 + laneLo;
        #pragma unroll
        for (int kk = 0; kk < 2; kk++) {
            int c = kk * 4 + laneHi;
            offB[n][kk] = r * 128 + ((c ^ (r & 7)) << 4);
        }
    }

    f32x4 acc[4][2];
    #pragma unroll
    for (int m = 0; m < 4; m++)
        #pragma unroll
        for (int n = 0; n < 2; n++)
            acc[m][n] = (f32x4){0.f, 0.f, 0.f, 0.f};

    for (int k0 = 0; k0 < KP; k0 += 64) {
        #pragma unroll
        for (int i = 0; i < 4; i++)
            __builtin_amdgcn_global_load_lds(
                (const __attribute__((address_space(1))) void*)(srcA[i] + k0),
                (__attribute__((address_space(3))) void*)(As + (i * 256 + tid) * 8),
                16, 0, 0);
        #pragma unroll
        for (int i = 0; i < 2; i++)
            __builtin_amdgcn_global_load_lds(
                (const __attribute__((address_space(1))) void*)(srcB[i] + k0),
                (__attribute__((address_space(3))) void*)(Bs + (i * 256 + tid) * 8),
                16, 0, 0);
        __syncthreads();

        bf16x8 af[4][2], bfr[2][2];
        #pragma unroll
        for (int m = 0; m < 4; m++)
            #pragma unroll
            for (int kk = 0; kk < 2; kk++)
                af[m][kk] = *(const bf16x8*)((const char*)As + offA[m][kk]);
        #pragma unroll
        for (int n = 0; n < 2; n++)
            #pragma unroll
            for (int kk = 0; kk < 2; kk++)
                bfr[n][kk] = *(const bf16x8*)((const char*)Bs + offB[n][kk]);
        #pragma unroll
        for (int m = 0; m < 4; m++)
            #pragma unroll
            for (int n = 0; n < 2; n++)
                #pragma unroll
                for (int kk = 0; kk < 2; kk++)
                    acc[m][n] = __builtin_amdgcn_mfma_f32_16x16x32_bf16(
                        af[m][kk], bfr[n][kk], acc[m][n], 0, 0, 0);
        __syncthreads();
    }

    int jnc = j * 4 + nc;
    int colT = laneLo;
    int rowB = laneHi * 4;
    #pragma unroll
    for (int n = 0; n < 2; n++) {
        int t = t0 + wn * 32 + n * 16 + colT;
        if (t >= NFRAMES) continue;
        size_t vrow = ((size_t)jnc * NFRAMES + t) * KP;
        #pragma unroll
        for (int m = 0; m < 4; m++) {
            int g = g0 + wm * 64 + m * 16 + rowB;
            if (g + 3 < NBINS) {
                bf16x4 o;
                #pragma unroll
                for (int r = 0; r < 4; r++)
                    o[r] = (bf16_t)fmaxf(acc[m][n][r] + bias[j * NBINS + g + r], 0.0f);
                *(bf16x4*)(V + vrow + g) = o;
            } else {
                #pragma unroll
                for (int r = 0; r < 4; r++) {
                    int gg = g + r;
                    if (gg < NBINS)
                        V[vrow + gg] = (bf16_t)fmaxf(acc[m][n][r] + bias[j * NBINS + gg], 0.0f);
                }
            }
        }
    }
}

// One block per (njc, frame): Y = V*phase, 4096-pt irfft, window, += into acc.
__global__ __launch_bounds__(256) void k_istft(const bf16_t* __restrict__ V,
        const unsigned* __restrict__ ph, float* __restrict__ acc, int pass) {
    int fr = pass + 4 * blockIdx.x;
    if (fr >= NFRAMES) return;
    int njc = blockIdx.y;
    int n = njc >> 3, j = (njc >> 1) & 3, c = njc & 1;
    int nc = n * 2 + c;
    __shared__ float2 yb[PADI(2048) + 2];
    __shared__ float2 zb[PADI(2047) + 2];
    int tid = threadIdx.x;
    size_t vrow = (((size_t)(j * 4 + nc)) * NFRAMES + fr) * KP;
    size_t prow = ((size_t)nc * NFRAMES + fr) * KP;
    for (int k = tid; k < NBINS; k += 256) {
        float v = (float)V[vrow + k];
        float2 p = unpack_bf2(ph[prow + k]);
        yb[PADI(k)] = make_float2(v * p.x, v * p.y);
    }
    __syncthreads();
    for (int k = tid; k < NH; k += 256) {
        float2 Yk = yb[PADI(k)];
        float2 Ym = yb[PADI(2048 - k)];
        float ex = 0.5f * (Yk.x + Ym.x), ey = 0.5f * (Yk.y - Ym.y);
        float wx = 0.5f * (Yk.x - Ym.x), wy = 0.5f * (Yk.y + Ym.y);
        float sw, cw;
        __sincosf((float)k * (TWO_PI / 4096.0f), &sw, &cw);
        float ox_ = cw * wx - sw * wy;
        float oy_ = cw * wy + sw * wx;
        zb[PADI(k)] = make_float2(ex - oy_, ey + ox_);
    }
    __syncthreads();
    float2* res = fft2048_r4(zb, yb, tid, +1.0f);
    float* dst = acc + (size_t)njc * OUTLEN + (size_t)fr * HOP;
    const float scale = 1.0f / 2048.0f;
    for (int m = tid; m < NH; m += 256) {
        float2 z = res[PADI(m)];
        int m2 = 2 * m;
        dst[m2]     += z.x * scale * hann_w(m2);
        dst[m2 + 1] += z.y * scale * hann_w(m2 + 1);
    }
}

__global__ __launch_bounds__(256) void k_final(const float* __restrict__ acc,
        float* __restrict__ out) {
    int t = blockIdx.x * 256 + threadIdx.x;
    int njc = blockIdx.y;
    if (t >= T_AUDIO) return;
    int q = t + PAD;
    int ib = q >> 10;
    float wsq = 0.0f;
    #pragma unroll
    for (int d = 0; d < 4; d++) {
        int i = ib - d;
        if (i >= 0 && i <= NFRAMES - 1) {
            int m = q - (i << 10);
            float w = hann_w(m);
            wsq += w * w;
        }
    }
    if (!(wsq > 1e-11f)) wsq = 1.0f;
    out[(size_t)njc * T_AUDIO + t] = acc[(size_t)njc * OUTLEN + q] / wsq;
}

extern "C" void kernel_launch(void* const* d_in, const int* in_sizes, int n_in,
                              void* d_out, int out_size, void* d_ws, size_t ws_size,
                              hipStream_t stream) {
    const float* audio = (const float*)d_in[0];
    const float* Wm    = (const float*)d_in[1];
    const float* bias  = (const float*)d_in[2];
    float* out = (float*)d_out;
    char* ws = (char*)d_ws;

    size_t szWb  = (size_t)4 * GP * KP * sizeof(bf16_t);        // 36.8 MB
    size_t szXb  = (size_t)4 * TPN * KP * sizeof(bf16_t);       //  8.7 MB
    size_t szPh  = (size_t)4 * NFRAMES * KP * sizeof(unsigned); // 14.6 MB
    size_t szV   = (size_t)16 * NFRAMES * KP * sizeof(bf16_t);  // 29.1 MB
    size_t szAcc = (size_t)16 * OUTLEN * sizeof(float);         // 28.4 MB

    bf16_t*   Wb   = (bf16_t*)ws;   ws += szWb;
    bf16_t*   Xb   = (bf16_t*)ws;   ws += szXb;
    unsigned* ph   = (unsigned*)ws; ws += szPh;
    bf16_t*   V    = (bf16_t*)ws;   ws += szV;
    float*    accb = (float*)ws;    ws += szAcc;
    if ((size_t)(ws - (char*)d_ws) > ws_size) return;

    hipMemsetAsync(Xb, 0, szXb, stream);
    hipMemsetAsync(accb, 0, szAcc, stream);

    k_convW<<<dim3((unsigned)((4ull * GP * KP / 8 + 255) / 256)), 256, 0, stream>>>(Wm, Wb);
    k_stft<<<dim3(4 * NFRAMES), 256, 0, stream>>>(audio, Xb, ph);
    k_gemm_mfma<<<dim3(28, 17, 4), 256, 0, stream>>>(Wb, bias, Xb, V);
    for (int pass = 0; pass < 4; pass++)
        k_istft<<<dim3(108, 16), 256, 0, stream>>>(V, ph, accb, pass);
    k_final<<<dim3((T_AUDIO + 255) / 256, 16), 256, 0, stream>>>(accb, out);
}